// Round 1
// baseline (433.129 us; speedup 1.0000x reference)
//
#include <hip/hip_runtime.h>
#include <hip/hip_bf16.h>

typedef unsigned short u16;
typedef __attribute__((ext_vector_type(8))) short short8;   // 8 bf16 (4 VGPRs)
typedef __attribute__((ext_vector_type(4))) float f32x4;    // MFMA accumulator
typedef __attribute__((ext_vector_type(4))) u16 u16x4;

static constexpr int Bb = 512, Tt = 256, Cc = 768, Hh = 64;

__device__ __forceinline__ u16 f2bf(float f) {
    __hip_bfloat16 h = __float2bfloat16(f);   // RNE
    union { __hip_bfloat16 h; u16 u; } v; v.h = h;
    return v.u;
}

// ---------------------------------------------------------------------------
// Kernel 0: Wt[n][k] = bf16(W_{n/64}[k][n%64]),  n in [0,192), k in [0,768)
// Stored [N][K] so MFMA B-fragments are contiguous-along-K 16B loads.
// ---------------------------------------------------------------------------
__global__ void wt_kernel(const float* __restrict__ Wq, const float* __restrict__ Wk,
                          const float* __restrict__ Wv, u16* __restrict__ Wt) {
    int idx = blockIdx.x * 256 + threadIdx.x;          // 192*768 = 147456 threads
    int n = idx / Cc, k = idx % Cc;
    const float* W = (n < 64) ? Wq : (n < 128) ? Wk : Wv;
    Wt[idx] = f2bf(W[k * Hh + (n & 63)]);
}

// ---------------------------------------------------------------------------
// Kernel 1: fused QKV projection.  out[m][n] = sum_k x[m][k] * Wt[n][k]
// Block = 256 thr (4 waves) = 64 rows of x; wave = 16 rows x 192 cols.
// q,k stored row-major bf16 [B*T][64]; v stored transposed [B][64][256].
// ---------------------------------------------------------------------------
__global__ __launch_bounds__(256) void proj_kernel(
        const float* __restrict__ x, const u16* __restrict__ Wt,
        u16* __restrict__ qw, u16* __restrict__ kw, u16* __restrict__ vw) {
    const int wave = threadIdx.x >> 6, l = threadIdx.x & 63;
    const int lrow = l & 15, lgrp = l >> 4;
    const int m0 = blockIdx.x * 64 + wave * 16;

    f32x4 acc[12];
#pragma unroll
    for (int i = 0; i < 12; ++i) acc[i] = (f32x4)0.f;

    const float* xrow = x + (size_t)(m0 + lrow) * Cc + lgrp * 8;
    const u16* wbase0 = Wt + (size_t)lrow * Cc + lgrp * 8;

#pragma unroll 2
    for (int kk = 0; kk < Cc; kk += 32) {
        float4 a0 = *(const float4*)(xrow + kk);
        float4 a1 = *(const float4*)(xrow + kk + 4);
        short8 af;
        af[0] = (short)f2bf(a0.x); af[1] = (short)f2bf(a0.y);
        af[2] = (short)f2bf(a0.z); af[3] = (short)f2bf(a0.w);
        af[4] = (short)f2bf(a1.x); af[5] = (short)f2bf(a1.y);
        af[6] = (short)f2bf(a1.z); af[7] = (short)f2bf(a1.w);
        const u16* wb = wbase0 + kk;
#pragma unroll
        for (int nt = 0; nt < 12; ++nt) {
            short8 bf = *(const short8*)(wb + (size_t)nt * 16 * Cc);
            acc[nt] = __builtin_amdgcn_mfma_f32_16x16x32_bf16(af, bf, acc[nt], 0, 0, 0);
        }
    }

    // Epilogue: D layout col = lane&15 (n), row = lgrp*4+reg (m)
    const int mrow = m0 + lgrp * 4;
#pragma unroll
    for (int nt = 0; nt < 12; ++nt) {
        int n = nt * 16 + lrow;
        if (nt < 4) {               // q
#pragma unroll
            for (int r = 0; r < 4; ++r)
                qw[(size_t)(mrow + r) * Hh + n] = f2bf(acc[nt][r]);
        } else if (nt < 8) {        // k
#pragma unroll
            for (int r = 0; r < 4; ++r)
                kw[(size_t)(mrow + r) * Hh + (n - 64)] = f2bf(acc[nt][r]);
        } else {                    // v -> transposed [B][64][256], pack 4 consecutive s
            int h = n - 128;
            int b = mrow >> 8, s = mrow & 255;
            u16x4 pk;
            pk[0] = f2bf(acc[nt][0]); pk[1] = f2bf(acc[nt][1]);
            pk[2] = f2bf(acc[nt][2]); pk[3] = f2bf(acc[nt][3]);
            *(u16x4*)(vw + (size_t)b * (Hh * Tt) + (size_t)h * Tt + s) = pk;
        }
    }
}

// ---------------------------------------------------------------------------
// Kernel 2: causal attention per batch.
// Block = (b, 64-row tile); wave = 16 query rows; full 256-col S with masking.
// ---------------------------------------------------------------------------
__global__ __launch_bounds__(256) void attn_kernel(
        const u16* __restrict__ qw, const u16* __restrict__ kw,
        const u16* __restrict__ vw, const int* __restrict__ pad,
        float* __restrict__ out) {
    __shared__ u16 Plds[4][16][264];   // +8 pad -> 528B row stride (16B aligned)

    const int wave = threadIdx.x >> 6, l = threadIdx.x & 63;
    const int lrow = l & 15, lgrp = l >> 4;
    const int b = blockIdx.x >> 2;
    const int i0 = (blockIdx.x & 3) * 64 + wave * 16;

    // Q fragments (A operand): row = lrow, k contiguous 8 at lgrp*8
    const u16* qbase = qw + ((size_t)b * Tt + i0 + lrow) * Hh + lgrp * 8;
    short8 qf0 = *(const short8*)(qbase);
    short8 qf1 = *(const short8*)(qbase + 32);

    // S = Q K^T / 8, with causal mask
    f32x4 sreg[16];
    const u16* kbase = kw + ((size_t)b * Tt + lrow) * Hh + lgrp * 8;
#pragma unroll
    for (int t = 0; t < 16; ++t) {
        short8 kf0 = *(const short8*)(kbase + (size_t)t * 16 * Hh);
        short8 kf1 = *(const short8*)(kbase + (size_t)t * 16 * Hh + 32);
        f32x4 s = (f32x4)0.f;
        s = __builtin_amdgcn_mfma_f32_16x16x32_bf16(qf0, kf0, s, 0, 0, 0);
        s = __builtin_amdgcn_mfma_f32_16x16x32_bf16(qf1, kf1, s, 0, 0, 0);
#pragma unroll
        for (int r = 0; r < 4; ++r) {
            int i = i0 + lgrp * 4 + r;      // query row
            int sidx = t * 16 + lrow;       // key index
            sreg[t][r] = (sidx <= i) ? s[r] * 0.125f : -1e30f;
        }
    }

    // Row max: in-lane over tiles, then across the 16 lanes sharing rows
    f32x4 mx = sreg[0];
#pragma unroll
    for (int t = 1; t < 16; ++t)
#pragma unroll
        for (int r = 0; r < 4; ++r) mx[r] = fmaxf(mx[r], sreg[t][r]);
#pragma unroll
    for (int m = 1; m <= 8; m <<= 1)
#pragma unroll
        for (int r = 0; r < 4; ++r) mx[r] = fmaxf(mx[r], __shfl_xor(mx[r], m, 64));

    // exp + row sum (masked entries underflow to exactly 0)
    f32x4 sm = (f32x4)0.f;
#pragma unroll
    for (int t = 0; t < 16; ++t)
#pragma unroll
        for (int r = 0; r < 4; ++r) {
            float p = __expf(sreg[t][r] - mx[r]);
            sreg[t][r] = p;
            sm[r] += p;
        }
#pragma unroll
    for (int m = 1; m <= 8; m <<= 1)
#pragma unroll
        for (int r = 0; r < 4; ++r) sm[r] += __shfl_xor(sm[r], m, 64);

    // P -> LDS (bf16) to re-layout for the PV A-operand (per-wave region,
    // same-wave LDS ops are processed in order -> no barrier needed)
#pragma unroll
    for (int t = 0; t < 16; ++t)
#pragma unroll
        for (int r = 0; r < 4; ++r)
            Plds[wave][lgrp * 4 + r][t * 16 + lrow] = f2bf(sreg[t][r]);

    // O = P @ V   (V transposed [B][64][256] so B-frags are contiguous in s)
    f32x4 o[4];
#pragma unroll
    for (int ht = 0; ht < 4; ++ht) o[ht] = (f32x4)0.f;
    const u16* vbase = vw + (size_t)b * (Hh * Tt) + (size_t)lrow * Tt + lgrp * 8;
#pragma unroll
    for (int ks = 0; ks < 8; ++ks) {
        short8 pa = *(const short8*)(&Plds[wave][lrow][ks * 32 + lgrp * 8]);
#pragma unroll
        for (int ht = 0; ht < 4; ++ht) {
            short8 vb = *(const short8*)(vbase + (size_t)ht * 16 * Tt + ks * 32);
            o[ht] = __builtin_amdgcn_mfma_f32_16x16x32_bf16(pa, vb, o[ht], 0, 0, 0);
        }
    }

    // Epilogue: divide by row sum; zero pad-masked query rows
#pragma unroll
    for (int r = 0; r < 4; ++r) {
        int i = i0 + lgrp * 4 + r;
        int pv = pad[b * Tt + i];
        float inv = (pv != 0) ? (1.0f / sm[r]) : 0.0f;
#pragma unroll
        for (int ht = 0; ht < 4; ++ht)
            out[((size_t)b * Tt + i) * Hh + ht * 16 + lrow] = o[ht][r] * inv;
    }
}

// ---------------------------------------------------------------------------
extern "C" void kernel_launch(void* const* d_in, const int* in_sizes, int n_in,
                              void* d_out, int out_size, void* d_ws, size_t ws_size,
                              hipStream_t stream) {
    const float* x  = (const float*)d_in[0];
    const float* Wq = (const float*)d_in[1];
    const float* Wk = (const float*)d_in[2];
    const float* Wv = (const float*)d_in[3];
    const int* pad  = (const int*)d_in[4];
    float* out = (float*)d_out;

    // Workspace layout (bf16): Wt [192][768] | q [B*T][64] | k [B*T][64] | Vt [B][64][256]
    u16* Wt = (u16*)d_ws;                                   // 294912 B
    u16* qw = (u16*)((char*)d_ws + 294912);
    u16* kw = qw + (size_t)Bb * Tt * Hh;
    u16* vw = kw + (size_t)Bb * Tt * Hh;

    wt_kernel<<<576, 256, 0, stream>>>(Wq, Wk, Wv, Wt);
    proj_kernel<<<(Bb * Tt) / 64, 256, 0, stream>>>(x, Wt, qw, kw, vw);
    attn_kernel<<<Bb * 4, 256, 0, stream>>>(qw, kw, vw, pad, out);
}

// Round 2
// 174.662 us; speedup vs baseline: 2.4798x; 2.4798x over previous
//
#include <hip/hip_runtime.h>
#include <hip/hip_bf16.h>

typedef unsigned short u16;
typedef unsigned int u32;
typedef __attribute__((ext_vector_type(8))) short short8;   // 8 bf16 (4 VGPRs)
typedef __attribute__((ext_vector_type(4))) float f32x4;    // MFMA accumulator
typedef __attribute__((ext_vector_type(4))) u16 u16x4;

static constexpr int Bb = 512, Tt = 256, Cc = 768, Hh = 64;

__device__ __forceinline__ u16 f2bf(float f) {
    __hip_bfloat16 h = __float2bfloat16(f);   // RNE
    union { __hip_bfloat16 h; u16 u; } v; v.h = h;
    return v.u;
}

__device__ __forceinline__ void gll16(const u16* g, u16* l) {
    __builtin_amdgcn_global_load_lds(
        (const __attribute__((address_space(1))) u32*)g,
        (__attribute__((address_space(3))) u32*)l, 16, 0, 0);
}

// ---------------------------------------------------------------------------
// Kernel 0: arrange Wq|Wk|Wv into k-chunked, PRE-SWIZZLED bf16 layout so the
// proj kernel can stage each 24 KB chunk with linear global_load_lds and read
// B-fragments at swizzled addresses (byte ^= (n&7)<<4) conflict-free.
// Chunk kc (k in [kc*64,kc*64+64)): byte lb = (n*128 + kl*2) ^ ((n&7)<<4).
// ---------------------------------------------------------------------------
__global__ void wt_kernel(const float* __restrict__ Wq, const float* __restrict__ Wk,
                          const float* __restrict__ Wv, u16* __restrict__ Wt) {
    int idx = blockIdx.x * 256 + threadIdx.x;          // 192*768
    int n = idx / Cc, k = idx % Cc;
    const float* W = (n < 64) ? Wq : (n < 128) ? Wk : Wv;
    float val = W[k * Hh + (n & 63)];
    int kc = k >> 6, kl = k & 63;
    int lb = (n * 128 + kl * 2) ^ ((n & 7) << 4);
    Wt[kc * 12288 + (lb >> 1)] = f2bf(val);
}

// ---------------------------------------------------------------------------
// Kernel 1: fused QKV projection, LDS-staged double-buffered MFMA GEMM.
// Block = 512 thr (8 waves as 2x4), tile 128 rows x 192 cols, K_STEP = 64.
// Wave (wr,wc) owns 64 rows x 48 cols = acc[4][3].
// x: reg-staged f32->bf16 (coalesced float4 loads, swizzled ds_write).
// Wt: global_load_lds width-16 from pre-swizzled chunks.
// ---------------------------------------------------------------------------
__global__ __launch_bounds__(512, 4) void proj_kernel(
        const float* __restrict__ x, const u16* __restrict__ Wt,
        u16* __restrict__ qw, u16* __restrict__ kw, u16* __restrict__ vw) {
    __shared__ u16 xs[2][8192];    // [128][64] bf16, swizzled
    __shared__ u16 ws[2][12288];   // [192][64] bf16, swizzled

    const int tid = threadIdx.x;
    const int wave = tid >> 6, l = tid & 63;
    const int lrow = l & 15, lgrp = l >> 4;
    const int wr = wave >> 2, wc = wave & 3;
    const size_t m0 = (size_t)blockIdx.x * 128;
    const int cswz = (lrow & 7) << 4;          // row&7 == lrow&7 for all frag rows

    // x stager: thread covers rows {j*32+xsr}, 16B piece xsc of the 256B row-chunk
    const int xsr = tid >> 4, xsc = tid & 15;
    const float* xg = x + (m0 + xsr) * Cc + xsc * 4;

    float4 xr[4];
    f32x4 acc[4][3];
#pragma unroll
    for (int i = 0; i < 4; ++i)
#pragma unroll
        for (int j = 0; j < 3; ++j) acc[i][j] = (f32x4)0.f;

#define XLOAD(kc_)                                                             \
    _Pragma("unroll")                                                          \
    for (int j = 0; j < 4; ++j)                                                \
        xr[j] = *(const float4*)(xg + (size_t)j * 32 * Cc + (kc_) * 64);

#define XWRITE(nb_)                                                            \
    _Pragma("unroll")                                                          \
    for (int j = 0; j < 4; ++j) {                                              \
        int row = j * 32 + xsr;                                                \
        u16x4 pk;                                                              \
        pk[0] = f2bf(xr[j].x); pk[1] = f2bf(xr[j].y);                          \
        pk[2] = f2bf(xr[j].z); pk[3] = f2bf(xr[j].w);                          \
        int off = (row * 128 + xsc * 8) ^ ((row & 7) << 4);                    \
        *(u16x4*)((char*)xs[nb_] + off) = pk;                                  \
    }

#define WTSTAGE(kc_, nb_)                                                      \
    _Pragma("unroll")                                                          \
    for (int i = 0; i < 3; ++i)                                                \
        gll16(Wt + (size_t)(kc_) * 12288 + i * 4096 + wave * 512 + l * 8,      \
              ws[nb_] + i * 4096 + wave * 512);

    // Prologue
    XLOAD(0); WTSTAGE(0, 0); XWRITE(0);
    __syncthreads();

    for (int kc = 0; kc < 12; ++kc) {
        const int cur = kc & 1, nxt = cur ^ 1;
        if (kc < 11) { XLOAD(kc + 1); WTSTAGE(kc + 1, nxt); }

        const char* xb = (const char*)xs[cur];
        const char* wb = (const char*)ws[cur];
#pragma unroll
        for (int ksub = 0; ksub < 2; ++ksub) {
            short8 af[4], bfr[3];
#pragma unroll
            for (int mrep = 0; mrep < 4; ++mrep)
                af[mrep] = *(const short8*)(xb +
                    (((wr * 64 + mrep * 16 + lrow) * 128 + ksub * 64 + lgrp * 16) ^ cswz));
#pragma unroll
            for (int ntl = 0; ntl < 3; ++ntl)
                bfr[ntl] = *(const short8*)(wb +
                    (((wc * 48 + ntl * 16 + lrow) * 128 + ksub * 64 + lgrp * 16) ^ cswz));
#pragma unroll
            for (int mrep = 0; mrep < 4; ++mrep)
#pragma unroll
                for (int ntl = 0; ntl < 3; ++ntl)
                    acc[mrep][ntl] = __builtin_amdgcn_mfma_f32_16x16x32_bf16(
                        af[mrep], bfr[ntl], acc[mrep][ntl], 0, 0, 0);
        }
        if (kc < 11) { XWRITE(nxt); }
        __syncthreads();
    }

    // Epilogue: D layout col = lane&15 (n), row = lgrp*4+reg (m)
#pragma unroll
    for (int mrep = 0; mrep < 4; ++mrep) {
        size_t m = m0 + wr * 64 + mrep * 16 + lgrp * 4;
#pragma unroll
        for (int ntl = 0; ntl < 3; ++ntl) {
            int n = wc * 48 + ntl * 16 + lrow;
            f32x4 a = acc[mrep][ntl];
            if (n < 64) {               // q
#pragma unroll
                for (int r = 0; r < 4; ++r)
                    qw[(m + r) * Hh + n] = f2bf(a[r]);
            } else if (n < 128) {       // k
#pragma unroll
                for (int r = 0; r < 4; ++r)
                    kw[(m + r) * Hh + (n - 64)] = f2bf(a[r]);
            } else {                    // v -> transposed [B][64][256]
                int b = (int)(m >> 8), s = (int)(m & 255);
                u16x4 pk;
                pk[0] = f2bf(a[0]); pk[1] = f2bf(a[1]);
                pk[2] = f2bf(a[2]); pk[3] = f2bf(a[3]);
                *(u16x4*)(vw + (size_t)b * (Hh * Tt) + (size_t)(n - 128) * Tt + s) = pk;
            }
        }
    }
#undef XLOAD
#undef XWRITE
#undef WTSTAGE
}

// ---------------------------------------------------------------------------
// Kernel 2: causal attention per batch (unchanged from round 0 — passed).
// ---------------------------------------------------------------------------
__global__ __launch_bounds__(256) void attn_kernel(
        const u16* __restrict__ qw, const u16* __restrict__ kw,
        const u16* __restrict__ vw, const int* __restrict__ pad,
        float* __restrict__ out) {
    __shared__ u16 Plds[4][16][264];

    const int wave = threadIdx.x >> 6, l = threadIdx.x & 63;
    const int lrow = l & 15, lgrp = l >> 4;
    const int b = blockIdx.x >> 2;
    const int i0 = (blockIdx.x & 3) * 64 + wave * 16;

    const u16* qbase = qw + ((size_t)b * Tt + i0 + lrow) * Hh + lgrp * 8;
    short8 qf0 = *(const short8*)(qbase);
    short8 qf1 = *(const short8*)(qbase + 32);

    f32x4 sreg[16];
    const u16* kbase = kw + ((size_t)b * Tt + lrow) * Hh + lgrp * 8;
#pragma unroll
    for (int t = 0; t < 16; ++t) {
        short8 kf0 = *(const short8*)(kbase + (size_t)t * 16 * Hh);
        short8 kf1 = *(const short8*)(kbase + (size_t)t * 16 * Hh + 32);
        f32x4 s = (f32x4)0.f;
        s = __builtin_amdgcn_mfma_f32_16x16x32_bf16(qf0, kf0, s, 0, 0, 0);
        s = __builtin_amdgcn_mfma_f32_16x16x32_bf16(qf1, kf1, s, 0, 0, 0);
#pragma unroll
        for (int r = 0; r < 4; ++r) {
            int i = i0 + lgrp * 4 + r;
            int sidx = t * 16 + lrow;
            sreg[t][r] = (sidx <= i) ? s[r] * 0.125f : -1e30f;
        }
    }

    f32x4 mx = sreg[0];
#pragma unroll
    for (int t = 1; t < 16; ++t)
#pragma unroll
        for (int r = 0; r < 4; ++r) mx[r] = fmaxf(mx[r], sreg[t][r]);
#pragma unroll
    for (int m = 1; m <= 8; m <<= 1)
#pragma unroll
        for (int r = 0; r < 4; ++r) mx[r] = fmaxf(mx[r], __shfl_xor(mx[r], m, 64));

    f32x4 sm = (f32x4)0.f;
#pragma unroll
    for (int t = 0; t < 16; ++t)
#pragma unroll
        for (int r = 0; r < 4; ++r) {
            float p = __expf(sreg[t][r] - mx[r]);
            sreg[t][r] = p;
            sm[r] += p;
        }
#pragma unroll
    for (int m = 1; m <= 8; m <<= 1)
#pragma unroll
        for (int r = 0; r < 4; ++r) sm[r] += __shfl_xor(sm[r], m, 64);

#pragma unroll
    for (int t = 0; t < 16; ++t)
#pragma unroll
        for (int r = 0; r < 4; ++r)
            Plds[wave][lgrp * 4 + r][t * 16 + lrow] = f2bf(sreg[t][r]);

    f32x4 o[4];
#pragma unroll
    for (int ht = 0; ht < 4; ++ht) o[ht] = (f32x4)0.f;
    const u16* vbase = vw + (size_t)b * (Hh * Tt) + (size_t)lrow * Tt + lgrp * 8;
#pragma unroll
    for (int ks = 0; ks < 8; ++ks) {
        short8 pa = *(const short8*)(&Plds[wave][lrow][ks * 32 + lgrp * 8]);
#pragma unroll
        for (int ht = 0; ht < 4; ++ht) {
            short8 vb = *(const short8*)(vbase + (size_t)ht * 16 * Tt + ks * 32);
            o[ht] = __builtin_amdgcn_mfma_f32_16x16x32_bf16(pa, vb, o[ht], 0, 0, 0);
        }
    }

#pragma unroll
    for (int r = 0; r < 4; ++r) {
        int i = i0 + lgrp * 4 + r;
        int pv = pad[b * Tt + i];
        float inv = (pv != 0) ? (1.0f / sm[r]) : 0.0f;
#pragma unroll
        for (int ht = 0; ht < 4; ++ht)
            out[((size_t)b * Tt + i) * Hh + ht * 16 + lrow] = o[ht][r] * inv;
    }
}

// ---------------------------------------------------------------------------
extern "C" void kernel_launch(void* const* d_in, const int* in_sizes, int n_in,
                              void* d_out, int out_size, void* d_ws, size_t ws_size,
                              hipStream_t stream) {
    const float* x  = (const float*)d_in[0];
    const float* Wq = (const float*)d_in[1];
    const float* Wk = (const float*)d_in[2];
    const float* Wv = (const float*)d_in[3];
    const int* pad  = (const int*)d_in[4];
    float* out = (float*)d_out;

    // Workspace (bf16): Wt [12][12288] | q [B*T][64] | k [B*T][64] | Vt [B][64][256]
    u16* Wt = (u16*)d_ws;                                   // 294912 B
    u16* qw = (u16*)((char*)d_ws + 294912);
    u16* kw = qw + (size_t)Bb * Tt * Hh;
    u16* vw = kw + (size_t)Bb * Tt * Hh;

    wt_kernel<<<576, 256, 0, stream>>>(Wq, Wk, Wv, Wt);
    proj_kernel<<<(Bb * Tt) / 128, 512, 0, stream>>>(x, Wt, qw, kw, vw);
    attn_kernel<<<Bb * 4, 256, 0, stream>>>(qw, kw, vw, pad, out);
}

// Round 3
// 150.247 us; speedup vs baseline: 2.8828x; 1.1625x over previous
//
#include <hip/hip_runtime.h>
#include <hip/hip_bf16.h>

typedef unsigned short u16;
typedef unsigned int u32;
typedef __attribute__((ext_vector_type(8))) short short8;   // 8 bf16 (4 VGPRs)
typedef __attribute__((ext_vector_type(4))) float f32x4;    // MFMA accumulator
typedef __attribute__((ext_vector_type(4))) u16 u16x4;

static constexpr int Bb = 512, Tt = 256, Cc = 768, Hh = 64;

__device__ __forceinline__ u16 f2bf(float f) {
    __hip_bfloat16 h = __float2bfloat16(f);   // RNE
    union { __hip_bfloat16 h; u16 u; } v; v.h = h;
    return v.u;
}

__device__ __forceinline__ void gll16(const u16* g, u16* l) {
    __builtin_amdgcn_global_load_lds(
        (const __attribute__((address_space(1))) u32*)g,
        (__attribute__((address_space(3))) u32*)l, 16, 0, 0);
}

// ---------------------------------------------------------------------------
// Kernel 0: arrange Wq|Wk|Wv into k-chunked, PRE-SWIZZLED bf16 layout so the
// proj kernel can stage each 24 KB chunk with linear global_load_lds and read
// B-fragments at swizzled addresses (byte ^= (n&7)<<4) conflict-free.
// ---------------------------------------------------------------------------
__global__ void wt_kernel(const float* __restrict__ Wq, const float* __restrict__ Wk,
                          const float* __restrict__ Wv, u16* __restrict__ Wt) {
    int idx = blockIdx.x * 256 + threadIdx.x;          // 192*768
    int n = idx / Cc, k = idx % Cc;
    const float* W = (n < 64) ? Wq : (n < 128) ? Wk : Wv;
    float val = W[k * Hh + (n & 63)];
    int kc = k >> 6, kl = k & 63;
    int lb = (n * 128 + kl * 2) ^ ((n & 7) << 4);
    Wt[kc * 12288 + (lb >> 1)] = f2bf(val);
}

// ---------------------------------------------------------------------------
// Kernel 1: fused QKV projection, LDS-staged double-buffered MFMA GEMM.
// Block = 512 thr (8 waves as 2x4), tile 128 rows x 192 cols, K_STEP = 64.
// NEW epilogue: LDS-bounce re-layout -> FRAGMENT-MAJOR q/k/v global buffers:
//   qf/kf: per 16-row tile, 2 frag blocks (h 0..31 / 32..63) of 1024 B; lane
//          l's 16 B at offset l*16 holds row (l&15), h = c*32+(l>>4)*8 ..+7.
//   vf:    per batch, [s-chunk 0..7][h-tile 0..3] 1024 B blocks; lane l holds
//          h = ht*16+(l&15), s = ks*32+(l>>4)*8 ..+7.
// attn then loads every MFMA fragment as ONE coalesced 1 KB wave-load.
// ---------------------------------------------------------------------------
__global__ __launch_bounds__(512, 4) void proj_kernel(
        const float* __restrict__ x, const u16* __restrict__ Wt,
        u16* __restrict__ qf, u16* __restrict__ kf, u16* __restrict__ vf) {
    __shared__ u16 smem[40960];   // loop: xs[2]=smem+{0,8192}, ws[2]=smem+16384+{0,12288}
                                  // epilogue: qk tile=smem[0..16384), vt=smem[16384..24576)
    const int tid = threadIdx.x;
    const int wave = tid >> 6, l = tid & 63;
    const int lrow = l & 15, lgrp = l >> 4;
    const int wr = wave >> 2, wc = wave & 3;
    const size_t m0 = (size_t)blockIdx.x * 128;
    const int cswz = (lrow & 7) << 4;

    const int xsr = tid >> 4, xsc = tid & 15;
    const float* xg = x + (m0 + xsr) * Cc + xsc * 4;

    float4 xr[4];
    f32x4 acc[4][3];
#pragma unroll
    for (int i = 0; i < 4; ++i)
#pragma unroll
        for (int j = 0; j < 3; ++j) acc[i][j] = (f32x4)0.f;

#define XLOAD(kc_)                                                             \
    _Pragma("unroll")                                                          \
    for (int j = 0; j < 4; ++j)                                                \
        xr[j] = *(const float4*)(xg + (size_t)j * 32 * Cc + (kc_) * 64);

#define XWRITE(nb_)                                                            \
    {                                                                          \
        u16* xb_ = smem + (nb_) * 8192;                                        \
        _Pragma("unroll")                                                      \
        for (int j = 0; j < 4; ++j) {                                          \
            int row = j * 32 + xsr;                                            \
            u16x4 pk;                                                          \
            pk[0] = f2bf(xr[j].x); pk[1] = f2bf(xr[j].y);                      \
            pk[2] = f2bf(xr[j].z); pk[3] = f2bf(xr[j].w);                      \
            int off = (row * 128 + xsc * 8) ^ ((row & 7) << 4);                \
            *(u16x4*)((char*)xb_ + off) = pk;                                  \
        }                                                                      \
    }

#define WTSTAGE(kc_, nb_)                                                      \
    {                                                                          \
        u16* wl_ = smem + 16384 + (nb_) * 12288;                               \
        _Pragma("unroll")                                                      \
        for (int i = 0; i < 3; ++i)                                            \
            gll16(Wt + (size_t)(kc_) * 12288 + i * 4096 + wave * 512 + l * 8,  \
                  wl_ + i * 4096 + wave * 512);                                \
    }

    XLOAD(0); WTSTAGE(0, 0); XWRITE(0);
    __syncthreads();

    for (int kc = 0; kc < 12; ++kc) {
        const int cur = kc & 1, nxt = cur ^ 1;
        if (kc < 11) { XLOAD(kc + 1); WTSTAGE(kc + 1, nxt); }

        const char* xb = (const char*)(smem + cur * 8192);
        const char* wb = (const char*)(smem + 16384 + cur * 12288);
#pragma unroll
        for (int ksub = 0; ksub < 2; ++ksub) {
            short8 af[4], bfr[3];
#pragma unroll
            for (int mrep = 0; mrep < 4; ++mrep)
                af[mrep] = *(const short8*)(xb +
                    (((wr * 64 + mrep * 16 + lrow) * 128 + ksub * 64 + lgrp * 16) ^ cswz));
#pragma unroll
            for (int ntl = 0; ntl < 3; ++ntl)
                bfr[ntl] = *(const short8*)(wb +
                    (((wc * 48 + ntl * 16 + lrow) * 128 + ksub * 64 + lgrp * 16) ^ cswz));
#pragma unroll
            for (int mrep = 0; mrep < 4; ++mrep)
#pragma unroll
                for (int ntl = 0; ntl < 3; ++ntl)
                    acc[mrep][ntl] = __builtin_amdgcn_mfma_f32_16x16x32_bf16(
                        af[mrep], bfr[ntl], acc[mrep][ntl], 0, 0, 0);
        }
        if (kc < 11) { XWRITE(nxt); }
        __syncthreads();
    }
#undef XLOAD
#undef XWRITE
#undef WTSTAGE

    // ---- Epilogue: scatter acc -> swizzled LDS tiles ----
    u16* qk = smem;            // [128 s][128 n] bf16, 256 B rows, XOR-swizzled
    u16* vt = smem + 16384;    // [64 h][128 s] bf16, 256 B rows, XOR-swizzled
#pragma unroll
    for (int mrep = 0; mrep < 4; ++mrep) {
        int sl = wr * 64 + mrep * 16 + lgrp * 4;       // local row (s)
#pragma unroll
        for (int ntl = 0; ntl < 3; ++ntl) {
            int n = wc * 48 + ntl * 16 + lrow;
            f32x4 a = acc[mrep][ntl];
            if (n < 128) {                              // q | k
#pragma unroll
                for (int r = 0; r < 4; ++r) {
                    int row = sl + r;
                    int off = (row * 256 + n * 2) ^ ((row & 7) << 4);
                    *(u16*)((char*)qk + off) = f2bf(a[r]);
                }
            } else {                                    // v (transposed)
                int h = n - 128;
                u16x4 pk;
                pk[0] = f2bf(a[0]); pk[1] = f2bf(a[1]);
                pk[2] = f2bf(a[2]); pk[3] = f2bf(a[3]);
                int off = (h * 256 + sl * 2) ^ ((h & 7) << 4);
                *(u16x4*)((char*)vt + off) = pk;
            }
        }
    }
    __syncthreads();

    // ---- Gather MFMA fragments, store fragment-major (coalesced 1 KB) ----
    const size_t rt0 = m0 >> 4;                 // first 16-row tile index
    const int bidx = (int)(m0 >> 8);            // batch
    const int sb5 = (int)((m0 & 255) >> 5);     // s-chunk base (0 or 4)
#pragma unroll
    for (int it = 0; it < 6; ++it) {
        int f = it * 8 + wave;                  // 48 fragments total
        const char* src;
        u16* dst;
        if (f < 16) {                           // Q frags
            int t = f >> 1, c = f & 1;
            int row = t * 16 + lrow;
            src = (const char*)qk + ((row * 256 + (c * 32 + lgrp * 8) * 2) ^ ((row & 7) << 4));
            dst = qf + ((rt0 + t) * 2 + c) * 512 + l * 8;
        } else if (f < 32) {                    // K frags
            int g = f - 16, t = g >> 1, c = g & 1;
            int row = t * 16 + lrow;
            src = (const char*)qk + ((row * 256 + 128 + (c * 32 + lgrp * 8) * 2) ^ ((row & 7) << 4));
            dst = kf + ((rt0 + t) * 2 + c) * 512 + l * 8;
        } else {                                // V frags
            int g = f - 32, ks = g >> 2, ht = g & 3;
            int row = ht * 16 + lrow;
            src = (const char*)vt + ((row * 256 + (ks * 32 + lgrp * 8) * 2) ^ ((row & 7) << 4));
            dst = vf + (size_t)bidx * 16384 + ((sb5 + ks) * 4 + ht) * 512 + l * 8;
        }
        short8 v = *(const short8*)src;
        *(short8*)dst = v;
    }
}

// ---------------------------------------------------------------------------
// Kernel 2: causal attention; ALL fragment loads are coalesced 1 KB wave-loads
// from the fragment-major qf/kf/vf buffers (L2-resident per batch).
// ---------------------------------------------------------------------------
__global__ __launch_bounds__(256) void attn_kernel(
        const u16* __restrict__ qf, const u16* __restrict__ kf,
        const u16* __restrict__ vf, const int* __restrict__ pad,
        float* __restrict__ out) {
    __shared__ u16 Plds[4][16][264];

    const int wave = threadIdx.x >> 6, l = threadIdx.x & 63;
    const int lrow = l & 15, lgrp = l >> 4;
    const int b = blockIdx.x >> 2;
    const int i0 = (blockIdx.x & 3) * 64 + wave * 16;

    const u16* qb = qf + (size_t)(b * 16 + (i0 >> 4)) * 1024 + l * 8;
    short8 q0 = *(const short8*)qb;
    short8 q1 = *(const short8*)(qb + 512);

    f32x4 sreg[16];
    const u16* kb = kf + (size_t)b * 16384 + l * 8;
#pragma unroll
    for (int t = 0; t < 16; ++t) {
        short8 k0 = *(const short8*)(kb + t * 1024);
        short8 k1 = *(const short8*)(kb + t * 1024 + 512);
        f32x4 s = (f32x4)0.f;
        s = __builtin_amdgcn_mfma_f32_16x16x32_bf16(q0, k0, s, 0, 0, 0);
        s = __builtin_amdgcn_mfma_f32_16x16x32_bf16(q1, k1, s, 0, 0, 0);
#pragma unroll
        for (int r = 0; r < 4; ++r) {
            int i = i0 + lgrp * 4 + r;      // query row
            int sidx = t * 16 + lrow;       // key index
            sreg[t][r] = (sidx <= i) ? s[r] * 0.125f : -1e30f;
        }
    }

    f32x4 mx = sreg[0];
#pragma unroll
    for (int t = 1; t < 16; ++t)
#pragma unroll
        for (int r = 0; r < 4; ++r) mx[r] = fmaxf(mx[r], sreg[t][r]);
#pragma unroll
    for (int m = 1; m <= 8; m <<= 1)
#pragma unroll
        for (int r = 0; r < 4; ++r) mx[r] = fmaxf(mx[r], __shfl_xor(mx[r], m, 64));

    f32x4 sm = (f32x4)0.f;
#pragma unroll
    for (int t = 0; t < 16; ++t)
#pragma unroll
        for (int r = 0; r < 4; ++r) {
            float p = __expf(sreg[t][r] - mx[r]);
            sreg[t][r] = p;
            sm[r] += p;
        }
#pragma unroll
    for (int m = 1; m <= 8; m <<= 1)
#pragma unroll
        for (int r = 0; r < 4; ++r) sm[r] += __shfl_xor(sm[r], m, 64);

#pragma unroll
    for (int t = 0; t < 16; ++t)
#pragma unroll
        for (int r = 0; r < 4; ++r)
            Plds[wave][lgrp * 4 + r][t * 16 + lrow] = f2bf(sreg[t][r]);

    f32x4 o[4];
#pragma unroll
    for (int ht = 0; ht < 4; ++ht) o[ht] = (f32x4)0.f;
    const u16* vb0 = vf + (size_t)b * 16384 + l * 8;
#pragma unroll
    for (int ks = 0; ks < 8; ++ks) {
        short8 pa = *(const short8*)(&Plds[wave][lrow][ks * 32 + lgrp * 8]);
#pragma unroll
        for (int ht = 0; ht < 4; ++ht) {
            short8 vbf = *(const short8*)(vb0 + (ks * 4 + ht) * 512);
            o[ht] = __builtin_amdgcn_mfma_f32_16x16x32_bf16(pa, vbf, o[ht], 0, 0, 0);
        }
    }

#pragma unroll
    for (int r = 0; r < 4; ++r) {
        int i = i0 + lgrp * 4 + r;
        int pv = pad[b * Tt + i];
        float inv = (pv != 0) ? (1.0f / sm[r]) : 0.0f;
#pragma unroll
        for (int ht = 0; ht < 4; ++ht)
            out[((size_t)b * Tt + i) * Hh + ht * 16 + lrow] = o[ht][r] * inv;
    }
}

// ---------------------------------------------------------------------------
extern "C" void kernel_launch(void* const* d_in, const int* in_sizes, int n_in,
                              void* d_out, int out_size, void* d_ws, size_t ws_size,
                              hipStream_t stream) {
    const float* x  = (const float*)d_in[0];
    const float* Wq = (const float*)d_in[1];
    const float* Wk = (const float*)d_in[2];
    const float* Wv = (const float*)d_in[3];
    const int* pad  = (const int*)d_in[4];
    float* out = (float*)d_out;

    // Workspace (u16 units): Wt 147456 | qf 8388608 | kf 8388608 | vf 8388608
    u16* Wt = (u16*)d_ws;
    u16* qf = Wt + 147456;
    u16* kf = qf + 8388608;
    u16* vf = kf + 8388608;

    wt_kernel<<<576, 256, 0, stream>>>(Wq, Wk, Wv, Wt);
    proj_kernel<<<(Bb * Tt) / 128, 512, 0, stream>>>(x, Wt, qf, kf, vf);
    attn_kernel<<<Bb * 4, 256, 0, stream>>>(qf, kf, vf, pad, out);
}